// Round 14
// baseline (153.220 us; speedup 1.0000x reference)
//
#include <hip/hip_runtime.h>
#include <stdint.h>

// Problem constants: B=32, S=10, D=4096, K=8192
#define B_ 32
#define S_ 10
#define D_ 4096
#define K_ 8192
#define RPB 21                 // rows per batch in A: 10 pq + 10 pp + 1 qq
#define M_REAL (B_ * RPB)      // 672

#define BM 256
#define BN 256
#define BK 32
#define M_PAD_MF 768           // 3 tiles of 256 (A padded with zeros)
#define KSPLIT 8
#define KCHUNK (D_ / KSPLIT)   // 512
#define NSTEP (KCHUNK / BK)    // 16

typedef _Float16 f16x8 __attribute__((ext_vector_type(8)));
typedef float f32x4 __attribute__((ext_vector_type(4)));
typedef unsigned short us4 __attribute__((ext_vector_type(4)));

__device__ __forceinline__ void async16(const void* g, void* l) {
  __builtin_amdgcn_global_load_lds(
      (const __attribute__((address_space(1))) unsigned int*)g,
      (__attribute__((address_space(3))) unsigned int*)l, 16, 0, 0);
}

// ---------------------------------------------------------------------------
// Prepass: build A rows (pq / pp / qq), quantize to a single f16 plane.
// ---------------------------------------------------------------------------
__global__ __launch_bounds__(256)
void build_a_f16(const float* __restrict__ p, const float* __restrict__ q,
                 unsigned short* __restrict__ Af) {
  size_t idx = (size_t)blockIdx.x * 256 + threadIdx.x;  // over M_PAD_MF * 1024 float4s
  int d4 = (int)(idx & 1023);
  int m = (int)(idx >> 10);
  float4 v = make_float4(0.f, 0.f, 0.f, 0.f);
  if (m < M_REAL) {
    int b = m / RPB;
    int r = m - b * RPB;
    const float4* q4 = (const float4*)(q + (size_t)(b * S_ + (S_ - 1)) * D_);
    if (r < S_) {
      const float4* p4 = (const float4*)(p + (size_t)(b * S_ + r) * D_);
      float4 pv = p4[d4]; float4 qv = q4[d4];
      v = make_float4(pv.x * qv.x, pv.y * qv.y, pv.z * qv.z, pv.w * qv.w);
    } else if (r < 2 * S_) {
      const float4* p4 = (const float4*)(p + (size_t)(b * S_ + (r - S_)) * D_);
      float4 pv = p4[d4];
      v = make_float4(pv.x * pv.x, pv.y * pv.y, pv.z * pv.z, pv.w * pv.w);
    } else {
      float4 qv = q4[d4];
      v = make_float4(qv.x * qv.x, qv.y * qv.y, qv.z * qv.z, qv.w * qv.w);
    }
  }
  us4 h;
  ((unsigned short*)&h)[0] = (unsigned short)__builtin_bit_cast(unsigned short, (_Float16)v.x);
  ((unsigned short*)&h)[1] = (unsigned short)__builtin_bit_cast(unsigned short, (_Float16)v.y);
  ((unsigned short*)&h)[2] = (unsigned short)__builtin_bit_cast(unsigned short, (_Float16)v.z);
  ((unsigned short*)&h)[3] = (unsigned short)__builtin_bit_cast(unsigned short, (_Float16)v.w);
  ((us4*)Af)[idx] = h;
}

// ---------------------------------------------------------------------------
// Fused MFMA GEMM: G[ks][m][k] = sum_{d in chunk ks} Af[m][d] * (W[k][d])^2
// BYTES-MINIMAL geometry: 256x256 tile halves L3->CU traffic vs 128^2
// (604 MB vs 1.2 GB total) -- the 12-round invariant is ~12-14 TB/s ingest,
// so bytes, not schedule, set the time.  96 tiles x KSPLIT=8 = 768 blocks
// = exactly 3 balanced rounds at 1 block/CU (96 KB LDS).
// 8 waves (2m x 4n), wave tile 128x64, acc[8][4] f32x4 (128 VGPR).
//   A (f16): global_load_lds, 2 issues/thread/step, pre-swizzled source.
//   W (f32): global_load_lds direct, 4 issues/thread/step; square+cvt at
//            FRAGMENT READ time (VALU co-issues with MFMA; no prepass).
// Proven R6 skeleton: full double-buffer, ONE __syncthreads per step.
// LDS 96 KB: Abuf0 @0 (16K) | Abuf1 @16K | Wbuf0 @32K (32K) | Wbuf1 @64K
// Swizzles (involutions, on DMA source and frag reads):
//   A row = 64 B  = 4 granules:  phys = g ^ ((row ^ (row>>2)) & 3)
//   W row = 128 B = 8 granules:  phys = g ^ (row & 7)
// G planes store only M_REAL=672 rows (ws cap): C-write guards row<672.
// ---------------------------------------------------------------------------
__global__ __launch_bounds__(512, 2)
void gemm_mfma(const unsigned short* __restrict__ Af, const float* __restrict__ W,
               float* __restrict__ G) {
  __shared__ unsigned short lds[49152];   // 96 KB
  const int tid = threadIdx.x;
  const int lane = tid & 63;
  const int wid = tid >> 6;               // 0..7
  const int m0 = blockIdx.y * BM;
  const int n0 = blockIdx.x * BN;
  const int ks = blockIdx.z;
  const int d_base = ks * KCHUNK;

  char* const ldsA = (char*)lds;          // A buffers @0, @16384
  char* const ldsW = (char*)lds + 32768;  // W buffers @+0, @+32768

  // ---- A staging: 2 async DMA issues/thread/step (16 KB f16 tile) ----
  const unsigned short* gpA[2];
  uint32_t offA[2];
#pragma unroll
  for (int e = 0; e < 2; ++e) {
    int c = e * 512 + tid;                // granule 0..1023
    int row = c >> 2;                     // 0..255
    int g = (c & 3) ^ ((row ^ (row >> 2)) & 3);
    gpA[e] = Af + (size_t)(m0 + row) * D_ + d_base + g * 8;
    offA[e] = (uint32_t)(c * 16);
  }

  // ---- W staging: 4 async DMA issues/thread/step (32 KB fp32 tile) ----
  const float* gpW[4];
  uint32_t offW[4];
#pragma unroll
  for (int e = 0; e < 4; ++e) {
    int c = e * 512 + tid;                // granule 0..2047
    int row = c >> 3;                     // 0..255
    int g = (c & 7) ^ (row & 7);
    gpW[e] = W + (size_t)(n0 + row) * D_ + d_base + g * 4;
    offW[e] = (uint32_t)(c * 16);
  }

  f32x4 acc[8][4];
#pragma unroll
  for (int i = 0; i < 8; ++i)
#pragma unroll
    for (int j = 0; j < 4; ++j) acc[i][j] = (f32x4){0.f, 0.f, 0.f, 0.f};

  const int wm = wid >> 2;        // 0..1 (m half, 128 rows each)
  const int wn = wid & 3;         // 0..3 (n quarter, 64 cols each)
  const int frow = lane & 15;
  const int k16 = lane >> 4;      // 0..3
  int aoff[8];
  int woffL[4], woffH[4];
#pragma unroll
  for (int f = 0; f < 8; ++f) {
    int ra = wm * 128 + f * 16 + frow;                   // 0..255
    aoff[f] = ra * 64 + ((k16 ^ ((ra ^ (ra >> 2)) & 3)) * 16);
  }
#pragma unroll
  for (int f = 0; f < 4; ++f) {
    int rw = wn * 64 + f * 16 + frow;                    // 0..255
    woffL[f] = rw * 128 + (((2 * k16) ^ (rw & 7)) * 16);
    woffH[f] = rw * 128 + (((2 * k16 + 1) ^ (rw & 7)) * 16);
  }

  // ---- prologue: stage step 0 entirely via DMA ----
#pragma unroll
  for (int e = 0; e < 2; ++e) async16(gpA[e], ldsA + offA[e]);
#pragma unroll
  for (int e = 0; e < 4; ++e) async16(gpW[e], ldsW + offW[e]);
  __syncthreads();   // step-0 tiles visible

  for (int i = 0; i < NSTEP; ++i) {
    // ---- top: prefetch step i+1 into the idle buffers (async DMA) ----
    const int dn = ((i + 1 < NSTEP) ? (i + 1) : i) * BK;   // clamped
    const uint32_t nbA = (uint32_t)(((i + 1) & 1) * 16384);
    const uint32_t nbW = (uint32_t)(((i + 1) & 1) * 32768);
#pragma unroll
    for (int e = 0; e < 2; ++e) async16(gpA[e] + dn, ldsA + nbA + offA[e]);
#pragma unroll
    for (int e = 0; e < 4; ++e) async16(gpW[e] + dn, ldsW + nbW + offW[e]);

    // ---- compute step i from buf[i&1] ----
    char* const cA = ldsA + (uint32_t)((i & 1) * 16384);
    char* const cW = ldsW + (uint32_t)((i & 1) * 32768);
    f16x8 aF[8];
#pragma unroll
    for (int f = 0; f < 8; ++f)
      aF[f] = *(const f16x8*)(cA + aoff[f]);
#pragma unroll
    for (int nf = 0; nf < 4; ++nf) {
      f32x4 lo = *(const f32x4*)(cW + woffL[nf]);
      f32x4 hi = *(const f32x4*)(cW + woffH[nf]);
      f16x8 wF;
      wF[0] = (_Float16)(lo[0] * lo[0]); wF[1] = (_Float16)(lo[1] * lo[1]);
      wF[2] = (_Float16)(lo[2] * lo[2]); wF[3] = (_Float16)(lo[3] * lo[3]);
      wF[4] = (_Float16)(hi[0] * hi[0]); wF[5] = (_Float16)(hi[1] * hi[1]);
      wF[6] = (_Float16)(hi[2] * hi[2]); wF[7] = (_Float16)(hi[3] * hi[3]);
#pragma unroll
      for (int mf = 0; mf < 8; ++mf)
        acc[mf][nf] = __builtin_amdgcn_mfma_f32_16x16x32_f16(aF[mf], wF, acc[mf][nf], 0, 0, 0);
    }

    __syncthreads();   // single barrier: drains DMA(i+1); step-i reads done
  }

  // ---- C write (row<672 guard; G planes store M_REAL rows) ----
  float* Gp = G + (size_t)ks * M_REAL * K_;
  const int crow = m0 + wm * 128;
  const int ccol = n0 + wn * 64;
#pragma unroll
  for (int mf = 0; mf < 8; ++mf)
#pragma unroll
    for (int nf = 0; nf < 4; ++nf)
#pragma unroll
      for (int r = 0; r < 4; ++r) {
        int row = crow + mf * 16 + (lane >> 4) * 4 + r;
        int col = ccol + nf * 16 + (lane & 15);
        if (row < M_REAL) Gp[(size_t)row * K_ + col] = acc[mf][nf][r];
      }
}

// ---------------------------------------------------------------------------
// Epilogue: sum 8 K-split planes, normalize, transpose-write.
// out[b][k][s] = -dot / (sqrt(pp)*sqrt(qq)*D)
// ---------------------------------------------------------------------------
__global__ __launch_bounds__(256)
void epilogue8(const float* __restrict__ G, float* __restrict__ out) {
  __shared__ float buf[256 * S_];
  const int tid = threadIdx.x;
  const int b = blockIdx.y;
  const int k0 = blockIdx.x * 256;
  const int k = k0 + tid;
  const size_t PL = (size_t)M_REAL * K_;
  const float* Gb = G + (size_t)b * RPB * K_ + k;
  float nqs = 0.f;
#pragma unroll
  for (int pl = 0; pl < KSPLIT; ++pl) nqs += Gb[pl * PL + 20 * K_];
  float nq = sqrtf(nqs);
#pragma unroll
  for (int s = 0; s < S_; ++s) {
    size_t od = (size_t)s * K_;
    size_t op = (size_t)(S_ + s) * K_;
    float dot = 0.f, pp = 0.f;
#pragma unroll
    for (int pl = 0; pl < KSPLIT; ++pl) {
      dot += Gb[pl * PL + od];
      pp  += Gb[pl * PL + op];
    }
    buf[tid * S_ + s] = -dot / (sqrtf(pp) * nq * (float)D_);
  }
  __syncthreads();
  float* ob = out + ((size_t)b * K_ + k0) * S_;
  for (int i = tid; i < 256 * S_; i += 256) ob[i] = buf[i];
}

// ===========================================================================
extern "C" void kernel_launch(void* const* d_in, const int* in_sizes, int n_in,
                              void* d_out, int out_size, void* d_ws, size_t ws_size,
                              hipStream_t stream) {
  const float* p = (const float*)d_in[0];
  const float* q = (const float*)d_in[1];
  const float* W = (const float*)d_in[2];
  float* out = (float*)d_out;

  // ws: Af [768][4096] f16 (6291456 B) | G [8][672][8192] f32 (176160768 B)
  // total 182452224 B  (< 197132288 confirmed available in R2/R3)
  uint8_t* w = (uint8_t*)d_ws;
  unsigned short* Af = (unsigned short*)w;
  float* G = (float*)(w + 6291456);

  build_a_f16<<<(M_PAD_MF * (D_ / 4)) / 256, 256, 0, stream>>>(p, q, Af);
  dim3 ggrid(K_ / BN, M_PAD_MF / BM, KSPLIT);   // (32, 3, 8) = 768 blocks, 1/CU, 3 rounds
  gemm_mfma<<<ggrid, 512, 0, stream>>>(Af, W, G);
  epilogue8<<<dim3(K_ / 256, B_), 256, 0, stream>>>(G, out);
}